// Round 17
// baseline (788.431 us; speedup 1.0000x reference)
//
#include <hip/hip_runtime.h>
#include <hip/hip_bf16.h>
#include <math.h>

#define NNODES 32768
#define NEDGES 524288
#define CCH 128
#define NLAYERS 3
#define NHEADS 4
#define HDIM 32
#define NB_GRAPH 64
#define SNODES 512
#define INDIM 80
#define HIDDEN 256
#define BNEPS 1e-5f
#define ATTNSCALE 0.17677669529663689f

typedef _Float16 f16;
typedef f16 half8_t __attribute__((ext_vector_type(8)));
typedef f16 half4_t __attribute__((ext_vector_type(4)));
typedef float float4_t __attribute__((ext_vector_type(4)));

__device__ __forceinline__ float gelu_f(float x) {
    return 0.5f * x * (1.0f + erff(x * 0.70710678118654752f));
}

// ---------------- CSR build ----------------
__global__ void k_count(const int* __restrict__ dst, int* __restrict__ deg) {
    int e = blockIdx.x * blockDim.x + threadIdx.x;
    if (e < NEDGES) atomicAdd(&deg[dst[e]], 1);
}

// scan + dinv fused
__global__ __launch_bounds__(1024) void k_scan(const int* __restrict__ deg,
                                               int* __restrict__ rowptr,
                                               int* __restrict__ cursor,
                                               float* __restrict__ dinv) {
    __shared__ int sa[1024], sb[1024];
    int t = threadIdx.x;
    int base = t * 32;
    int local[32];
    int s = 0;
    #pragma unroll
    for (int i = 0; i < 32; i++) {
        int d = deg[base + i];
        local[i] = s; s += d;
        dinv[base + i] = rsqrtf((float)(d + 1));
    }
    sa[t] = s;
    __syncthreads();
    int* sp = sa; int* dp = sb;
    for (int off = 1; off < 1024; off <<= 1) {
        dp[t] = (t >= off) ? sp[t] + sp[t - off] : sp[t];
        __syncthreads();
        int* tmp = sp; sp = dp; dp = tmp;
    }
    int excl = (t == 0) ? 0 : sp[t - 1];
    #pragma unroll
    for (int i = 0; i < 32; i++) {
        int v = excl + local[i];
        rowptr[base + i] = v;
        cursor[base + i] = v;
    }
    if (t == 1023) rowptr[NNODES] = sp[1023];
}

__global__ void k_fill_edges(const int* __restrict__ src, const int* __restrict__ dst,
                             int* __restrict__ cursor, int* __restrict__ col) {
    int e = blockIdx.x * blockDim.x + threadIdx.x;
    if (e >= NEDGES) return;
    int pos = atomicAdd(&cursor[dst[e]], 1);
    col[pos] = src[e];
}

// ---------------- concat (padded to K=128) ----------------
__global__ void k_concat(const float* __restrict__ x, const float* __restrict__ pe,
                         float* __restrict__ out) {
    int gid = blockIdx.x * blockDim.x + threadIdx.x;
    if (gid >= NNODES * 32) return;
    int n = gid >> 5, q = gid & 31;
    float4 v = {0.f, 0.f, 0.f, 0.f};
    if (q < 16)      v = ((const float4*)x)[(size_t)n * 16 + q];
    else if (q < 20) v = ((const float4*)pe)[(size_t)n * 4 + (q - 16)];
    ((float4*)out)[gid] = v;
}

// ---------------- merged weight conversion ----------------
__device__ __forceinline__ void wconv_one(const float* __restrict__ src,
                                          f16* __restrict__ hi, f16* __restrict__ lo,
                                          int idx, int Nn, int Ks, int Kp, int trans,
                                          int ostride) {
    int per = Nn * Kp;
    int l = idx / per, r = idx % per;
    int n = r / Kp, k = r % Kp;
    float v = 0.f;
    if (k < Ks)
        v = trans ? src[(size_t)l * Nn * Ks + (size_t)n * Ks + k]
                  : src[(size_t)l * Ks * Nn + (size_t)k * Nn + n];
    f16 h = (f16)v;
    size_t o = (size_t)l * ostride + r;
    hi[o] = h;
    lo[o] = (f16)(v - (float)h);
}

__global__ void k_wconv_all(const float* __restrict__ W_emb, const float* __restrict__ gcn_w,
                            const float* __restrict__ in_w, const float* __restrict__ out_w,
                            const float* __restrict__ m1, const float* __restrict__ m2,
                            f16* embh, f16* embl, f16* cwh, f16* cwl,
                            f16* outh, f16* outl, f16* m1h, f16* m1l,
                            f16* m2h, f16* m2l) {
    int gid = blockIdx.x * blockDim.x + threadIdx.x;
    if (gid < 16384) {
        wconv_one(W_emb, embh, embl, gid, 128, 80, 128, 0, 128 * 128);
    } else if (gid < 65536) {
        wconv_one(gcn_w, cwh, cwl, gid - 16384, 128, 128, 128, 0, 512 * 128);
    } else if (gid < 212992) {
        wconv_one(in_w, cwh + 128 * 128, cwl + 128 * 128, gid - 65536, 384, 128, 128, 1, 512 * 128);
    } else if (gid < 262144) {
        wconv_one(out_w, outh, outl, gid - 212992, 128, 128, 128, 1, 128 * 128);
    } else if (gid < 360448) {
        wconv_one(m1, m1h, m1l, gid - 262144, 256, 128, 128, 0, 256 * 128);
    } else if (gid < 458752) {
        wconv_one(m2, m2h, m2l, gid - 360448, 128, 256, 256, 0, 128 * 256);
    }
}

// ---------------- split-f16 MFMA GEMM ----------------
// STATS (requires N==128, !SPLIT): epilogue adds R1 (RESID=1), writes pre-BN value,
// and accumulates per-block channel stats into part[blockIdx.y*256 + ...] using
// LDS aliased onto the dead A-staging buffers (no extra LDS).
template<int ACT, bool SPLIT, bool STATS, int RESID>
__global__ __launch_bounds__(256) void k_gemm_mfma(
        const float* __restrict__ A, const f16* __restrict__ Whi,
        const f16* __restrict__ Wlo, const float* __restrict__ bias,
        const float* __restrict__ rowscale, float* __restrict__ C,
        int M, int N, int K, f16* __restrict__ C2h,
        const float* __restrict__ bias2, f16* __restrict__ Cf16,
        const float* __restrict__ R1, float* __restrict__ part) {
    __shared__ f16 Ah[128 * 40];
    __shared__ f16 Al[128 * 40];
    __shared__ f16 Bh[128 * 40];
    __shared__ f16 Bl[128 * 40];
    const int t = threadIdx.x;
    const int bm = blockIdx.y * 128, bn = blockIdx.x * 128;
    const int w = t >> 6, lane = t & 63;
    const int g = lane >> 4, q = lane & 15;

    float4_t acc[2][8];
    #pragma unroll
    for (int mt = 0; mt < 2; mt++)
        #pragma unroll
        for (int nt = 0; nt < 8; nt++)
            acc[mt][nt] = (float4_t){0.f, 0.f, 0.f, 0.f};

    const int srow = t >> 1, shf = (t & 1) * 16;

    for (int kc = 0; kc < K; kc += 32) {
        {
            const float* ap = A + (size_t)(bm + srow) * K + kc + shf;
            float va[16];
            *(float4*)&va[0]  = ((const float4*)ap)[0];
            *(float4*)&va[4]  = ((const float4*)ap)[1];
            *(float4*)&va[8]  = ((const float4*)ap)[2];
            *(float4*)&va[12] = ((const float4*)ap)[3];
            half8_t h0, h1, l0, l1;
            #pragma unroll
            for (int j = 0; j < 8; j++) {
                f16 h = (f16)va[j];
                h0[j] = h; l0[j] = (f16)(va[j] - (float)h);
            }
            #pragma unroll
            for (int j = 0; j < 8; j++) {
                f16 h = (f16)va[8 + j];
                h1[j] = h; l1[j] = (f16)(va[8 + j] - (float)h);
            }
            *(half8_t*)&Ah[srow * 40 + shf]     = h0;
            *(half8_t*)&Ah[srow * 40 + shf + 8] = h1;
            *(half8_t*)&Al[srow * 40 + shf]     = l0;
            *(half8_t*)&Al[srow * 40 + shf + 8] = l1;
        }
        {
            const f16* bp = Whi + (size_t)(bn + srow) * K + kc + shf;
            *(half8_t*)&Bh[srow * 40 + shf]     = ((const half8_t*)bp)[0];
            *(half8_t*)&Bh[srow * 40 + shf + 8] = ((const half8_t*)bp)[1];
            const f16* lp = Wlo + (size_t)(bn + srow) * K + kc + shf;
            *(half8_t*)&Bl[srow * 40 + shf]     = ((const half8_t*)lp)[0];
            *(half8_t*)&Bl[srow * 40 + shf + 8] = ((const half8_t*)lp)[1];
        }
        __syncthreads();

        half8_t ah[2], al[2];
        #pragma unroll
        for (int mt = 0; mt < 2; mt++) {
            ah[mt] = *(half8_t*)&Ah[(w * 32 + mt * 16 + q) * 40 + g * 8];
            al[mt] = *(half8_t*)&Al[(w * 32 + mt * 16 + q) * 40 + g * 8];
        }
        #pragma unroll
        for (int nt = 0; nt < 8; nt++) {
            half8_t bh = *(half8_t*)&Bh[(nt * 16 + q) * 40 + g * 8];
            half8_t bl = *(half8_t*)&Bl[(nt * 16 + q) * 40 + g * 8];
            #pragma unroll
            for (int mt = 0; mt < 2; mt++) {
                acc[mt][nt] = __builtin_amdgcn_mfma_f32_16x16x32_f16(ah[mt], bh, acc[mt][nt], 0, 0, 0);
                acc[mt][nt] = __builtin_amdgcn_mfma_f32_16x16x32_f16(al[mt], bh, acc[mt][nt], 0, 0, 0);
                acc[mt][nt] = __builtin_amdgcn_mfma_f32_16x16x32_f16(ah[mt], bl, acc[mt][nt], 0, 0, 0);
            }
        }
        __syncthreads();
    }

    float sv[8], sq2[8];
    if (STATS) {
        #pragma unroll
        for (int nt = 0; nt < 8; nt++) { sv[nt] = 0.f; sq2[nt] = 0.f; }
    }

    #pragma unroll
    for (int mt = 0; mt < 2; mt++) {
        #pragma unroll
        for (int r = 0; r < 4; r++) {
            int row = bm + w * 32 + mt * 16 + 4 * g + r;
            if constexpr (SPLIT) {
                if (blockIdx.x == 0) {
                    float rs = rowscale[row];
                    #pragma unroll
                    for (int nt = 0; nt < 8; nt++) {
                        int cn = bn + nt * 16 + q;
                        Cf16[(size_t)row * 128 + cn] = (f16)(acc[mt][nt][r] * rs);
                    }
                } else {
                    float ksc = (blockIdx.x == 2) ? ATTNSCALE : 1.0f;
                    #pragma unroll
                    for (int nt = 0; nt < 8; nt++) {
                        int cn2 = bn - 128 + nt * 16 + q;
                        C2h[(size_t)row * 384 + cn2] =
                            (f16)((acc[mt][nt][r] + bias2[cn2]) * ksc);
                    }
                }
            } else {
                float rs = rowscale ? rowscale[row] : 1.0f;
                #pragma unroll
                for (int nt = 0; nt < 8; nt++) {
                    int cn = bn + nt * 16 + q;
                    float v = acc[mt][nt][r] + (bias ? bias[cn] : 0.0f);
                    v *= rs;
                    if (RESID == 1) v += R1[(size_t)row * 128 + cn];
                    if (ACT == 1) v = fmaxf(v, 0.0f);
                    C[(size_t)row * N + cn] = v;
                    if (STATS) { sv[nt] += v; sq2[nt] = fmaf(v, v, sq2[nt]); }
                }
            }
        }
    }

    if (STATS) {
        float* sredS = (float*)Ah;  // aliased dead staging LDS
        float* sredQ = (float*)Al;
        #pragma unroll
        for (int nt = 0; nt < 8; nt++) {
            sv[nt]  += __shfl_xor(sv[nt], 16);  sv[nt]  += __shfl_xor(sv[nt], 32);
            sq2[nt] += __shfl_xor(sq2[nt], 16); sq2[nt] += __shfl_xor(sq2[nt], 32);
        }
        if (lane < 16) {
            #pragma unroll
            for (int nt = 0; nt < 8; nt++) {
                sredS[w * 128 + nt * 16 + lane] = sv[nt];
                sredQ[w * 128 + nt * 16 + lane] = sq2[nt];
            }
        }
        __syncthreads();
        if (t < 128) {
            float a = 0.f, b = 0.f;
            #pragma unroll
            for (int ww = 0; ww < 4; ww++) {
                a += sredS[ww * 128 + t];
                b += sredQ[ww * 128 + t];
            }
            part[blockIdx.y * 256 + t]       = a;
            part[blockIdx.y * 256 + 128 + t] = b;
        }
    }
}

// ---------------- GCN gather (f16 table, fp32 accum) ----------------
__global__ __launch_bounds__(256) void k_gcn_gather_f16(
        const int* __restrict__ rowptr, const int* __restrict__ col,
        const f16* __restrict__ xws, const float* __restrict__ dinv,
        const float* __restrict__ bias, float* __restrict__ loc) {
    int t = threadIdx.x;
    int node = blockIdx.x * 16 + (t >> 4);
    int q = t & 15;
    int r0 = rowptr[node], r1 = rowptr[node + 1];
    half8_t sv = ((const half8_t*)(xws + (size_t)node * CCH))[q];
    float acc[8];
    #pragma unroll
    for (int i = 0; i < 8; i++) acc[i] = (float)sv[i];
    for (int j = r0; j < r1; j++) {
        int s = col[j];
        half8_t v = ((const half8_t*)(xws + (size_t)s * CCH))[q];
        #pragma unroll
        for (int i = 0; i < 8; i++) acc[i] += (float)v[i];
    }
    float dv = dinv[node];
    float4 b0 = ((const float4*)bias)[2 * q];
    float4 b1 = ((const float4*)bias)[2 * q + 1];
    float4 o0, o1;
    o0.x = fmaf(acc[0], dv, b0.x); o0.y = fmaf(acc[1], dv, b0.y);
    o0.z = fmaf(acc[2], dv, b0.z); o0.w = fmaf(acc[3], dv, b0.w);
    o1.x = fmaf(acc[4], dv, b1.x); o1.y = fmaf(acc[5], dv, b1.y);
    o1.z = fmaf(acc[6], dv, b1.z); o1.w = fmaf(acc[7], dv, b1.w);
    float* lp = loc + (size_t)node * CCH + q * 8;
    ((float4*)lp)[0] = o0;
    ((float4*)lp)[1] = o1;
}

// ---------------- BatchNorm ----------------
__global__ __launch_bounds__(256) void k_bn_stats(const float* __restrict__ a,
                                                  const float* __restrict__ b,
                                                  float* __restrict__ part) {
    __shared__ float s1[256], s2[256];
    int t = threadIdx.x, blk = blockIdx.x;
    int c = t & 127, half = t >> 7;
    float sum = 0.f, sq = 0.f;
    for (int i = 0; i < 128; i++) {
        size_t r = (size_t)blk * 256 + half + 2 * i;
        float v = a[r * CCH + c] + b[r * CCH + c];
        sum += v;
        sq = fmaf(v, v, sq);
    }
    s1[t] = sum; s2[t] = sq;
    __syncthreads();
    if (t < 128) {
        part[blk * 256 + t]       = s1[t] + s1[t + 128];
        part[blk * 256 + 128 + t] = s2[t] + s2[t + 128];
    }
}

// single-BN finalize (1024 thr, 8 slices), nblk partials
__global__ __launch_bounds__(1024) void k_bn_finalize(const float* __restrict__ part,
                                                      int nblk,
                                                      const float* __restrict__ g,
                                                      const float* __restrict__ be,
                                                      float* __restrict__ sc,
                                                      float* __restrict__ sh) {
    __shared__ float rs_[1024], rq_[1024];
    int t = threadIdx.x;
    int c = t & 127, sl = t >> 7;
    float s = 0.f, sq = 0.f;
    for (int bk = sl; bk < nblk; bk += 8) {
        s  += part[bk * 256 + c];
        sq += part[bk * 256 + 128 + c];
    }
    rs_[sl * 128 + c] = s;
    rq_[sl * 128 + c] = sq;
    __syncthreads();
    if (t < 128) {
        float ss = 0.f, qq = 0.f;
        #pragma unroll
        for (int k = 0; k < 8; k++) { ss += rs_[k * 128 + t]; qq += rq_[k * 128 + t]; }
        float mu = ss / (float)NNODES;
        float var = qq / (float)NNODES - mu * mu;
        float rsv = rsqrtf(var + BNEPS);
        float gg = g[t] * rsv;
        sc[t] = gg;
        sh[t] = be[t] - mu * gg;
    }
}

// dual-BN finalize: BN1 from part1[nblk1] (slices 0-3), BN2 from part2[nblk2] (4-7)
__global__ __launch_bounds__(1024) void k_bn_finalize2(
        const float* __restrict__ part1, int nblk1,
        const float* __restrict__ part2, int nblk2,
        const float* __restrict__ g1, const float* __restrict__ be1,
        const float* __restrict__ g2, const float* __restrict__ be2,
        float* __restrict__ sc1, float* __restrict__ sh1,
        float* __restrict__ sc2, float* __restrict__ sh2) {
    __shared__ float rs_[1024], rq_[1024];
    int t = threadIdx.x;
    int c = t & 127, sl = t >> 7;
    const float* p = (sl < 4) ? part1 : part2;
    int nblk = (sl < 4) ? nblk1 : nblk2;
    int s0 = sl & 3;
    float s = 0.f, sq = 0.f;
    for (int bk = s0; bk < nblk; bk += 4) {
        s  += p[bk * 256 + c];
        sq += p[bk * 256 + 128 + c];
    }
    rs_[sl * 128 + c] = s;
    rq_[sl * 128 + c] = sq;
    __syncthreads();
    if (t < 256) {
        int which = t >> 7, cc = t & 127;
        int o = which * 512;
        float ss = 0.f, qq = 0.f;
        #pragma unroll
        for (int k = 0; k < 4; k++) { ss += rs_[o + k * 128 + cc]; qq += rq_[o + k * 128 + cc]; }
        float mu = ss / (float)NNODES;
        float var = qq / (float)NNODES - mu * mu;
        float rsv = rsqrtf(var + BNEPS);
        if (which == 0) { float gg = g1[cc] * rsv; sc1[cc] = gg; sh1[cc] = be1[cc] - mu * gg; }
        else            { float gg = g2[cc] * rsv; sc2[cc] = gg; sh2[cc] = be2[cc] - mu * gg; }
    }
}

// h = gelu(bn(a)) single-input
__global__ void k_bn_apply1g(const float* __restrict__ a,
                             const float* __restrict__ sc, const float* __restrict__ sh,
                             float* __restrict__ out) {
    int gid = blockIdx.x * blockDim.x + threadIdx.x;
    if (gid >= NNODES * 32) return;
    int c = (gid & 31) * 4;
    float4 av = ((const float4*)a)[gid];
    float xs[4] = {av.x, av.y, av.z, av.w};
    float r[4];
    #pragma unroll
    for (int j = 0; j < 4; j++) r[j] = gelu_f(fmaf(xs[j], sc[c + j], sh[c + j]));
    float4 o = {r[0], r[1], r[2], r[3]};
    ((float4*)out)[gid] = o;
}

// A = bn1(Bb+h) + bn2(scr)   (scr already holds S2 = outproj + h)
__global__ void k_bn_apply2(const float* __restrict__ Bb, const float* __restrict__ h,
                            const float* __restrict__ scr,
                            const float* __restrict__ sc1, const float* __restrict__ sh1,
                            const float* __restrict__ sc2, const float* __restrict__ sh2,
                            float* __restrict__ A) {
    int gid = blockIdx.x * blockDim.x + threadIdx.x;
    if (gid >= NNODES * 32) return;
    int c = (gid & 31) * 4;
    float4 bv = ((const float4*)Bb)[gid];
    float4 hv = ((const float4*)h)[gid];
    float4 sv = ((const float4*)scr)[gid];
    float b4[4] = {bv.x, bv.y, bv.z, bv.w};
    float h4[4] = {hv.x, hv.y, hv.z, hv.w};
    float s4[4] = {sv.x, sv.y, sv.z, sv.w};
    float r[4];
    #pragma unroll
    for (int j = 0; j < 4; j++) {
        float x1 = b4[j] + h4[j];
        r[j] = fmaf(x1, sc1[c + j], sh1[c + j]) + fmaf(s4[j], sc2[c + j], sh2[c + j]);
    }
    float4 o = {r[0], r[1], r[2], r[3]};
    ((float4*)A)[gid] = o;
}

// ---------------- flash MFMA attention (f16 qkv input; 512 threads, 8 waves) ----------
__global__ __launch_bounds__(512) void k_attn_flash(const f16* __restrict__ qkv,
                                                    float* __restrict__ ao) {
    __shared__ f16 Ks[512 * 40];
    __shared__ f16 VT[32 * 512];
    const int bh = blockIdx.x;
    const int b = bh >> 2, hh = bh & 3;
    const int t = threadIdx.x;
    const int lane = t & 63, wave = t >> 6;
    const int g = lane >> 4, q16 = lane & 15;

    const f16* base = qkv + (size_t)b * SNODES * 384;

    #pragma unroll
    for (int it = 0; it < 4; it++) {
        int u = it * 512 + t;
        int row = u >> 2, c = u & 3;
        half8_t hv = *(const half8_t*)(base + (size_t)row * 384 + CCH + hh * HDIM + c * 8);
        *(half8_t*)(Ks + row * 40 + c * 8) = hv;
    }

    #pragma unroll
    for (int it = 0; it < 8; it++) {
        int j4 = (t >> 3) & 3;
        int n  = it * 64 + ((t >> 5) & 15) * 4 + j4;
        int c  = t & 7;
        half4_t hv = *(const half4_t*)(base + (size_t)n * 384 + 2 * CCH + hh * HDIM + c * 4);
        float4 v = {(float)hv[0], (float)hv[1], (float)hv[2], (float)hv[3]};
        float4 u1;
        u1.x = __shfl_xor(v.x, 8); u1.y = __shfl_xor(v.y, 8);
        u1.z = __shfl_xor(v.z, 8); u1.w = __shfl_xor(v.w, 8);
        float4 w;
        if ((t & 8) == 0) { w.x = v.x;  w.y = u1.x; w.z = v.z;  w.w = u1.z; }
        else              { w.x = u1.y; w.y = v.y;  w.z = u1.w; w.w = v.w;  }
        float4 u2;
        u2.x = __shfl_xor(w.x, 16); u2.y = __shfl_xor(w.y, 16);
        u2.z = __shfl_xor(w.z, 16); u2.w = __shfl_xor(w.w, 16);
        float4 o;
        if ((t & 16) == 0) { o.x = w.x;  o.y = w.y;  o.z = u2.x; o.w = u2.y; }
        else               { o.x = u2.z; o.y = u2.w; o.z = w.z;  o.w = w.w;  }
        int hd = c * 4 + j4;
        int n0 = it * 64 + ((t >> 5) & 15) * 4;
        half4_t pk;
        pk[0] = (f16)o.x; pk[1] = (f16)o.y; pk[2] = (f16)o.z; pk[3] = (f16)o.w;
        int pos = ((n0 >> 2) + hd) & 127;
        *(half4_t*)(VT + hd * 512 + pos * 4) = pk;
    }
    __syncthreads();

    for (int j = 0; j < 4; j++) {
        int qt = wave * 4 + j;

        half8_t qf = *(const half8_t*)(base + (size_t)(qt * 16 + q16) * 384 + hh * HDIM + g * 8);

        float m = -1e30f, l = 0.f;
        float4_t oa0 = {0.f, 0.f, 0.f, 0.f}, oa1 = {0.f, 0.f, 0.f, 0.f};

        for (int ci = 0; ci < 4; ci++) {
            float4_t acc[8];
            #pragma unroll
            for (int ktl = 0; ktl < 8; ktl++) {
                half8_t kf = *(half8_t*)(Ks + ((ci * 8 + ktl) * 16 + q16) * 40 + g * 8);
                float4_t z = {0.f, 0.f, 0.f, 0.f};
                acc[ktl] = __builtin_amdgcn_mfma_f32_16x16x32_f16(kf, qf, z, 0, 0, 0);
            }

            float cm = -1e30f;
            #pragma unroll
            for (int ktl = 0; ktl < 8; ktl++)
                cm = fmaxf(cm, fmaxf(fmaxf(acc[ktl][0], acc[ktl][1]),
                                     fmaxf(acc[ktl][2], acc[ktl][3])));
            cm = fmaxf(cm, __shfl_xor(cm, 16));
            cm = fmaxf(cm, __shfl_xor(cm, 32));

            float mn = fmaxf(m, cm);
            float scq = __expf(m - mn);
            m = mn;
            l *= scq;
            #pragma unroll
            for (int r = 0; r < 4; r++) {
                float scr_ = __shfl(scq, 4 * g + r);
                oa0[r] *= scr_;
                oa1[r] *= scr_;
            }

            half8_t pa[4];
            #pragma unroll
            for (int Tl = 0; Tl < 4; Tl++) {
                #pragma unroll
                for (int i = 0; i < 4; i++) {
                    float e0 = __expf(acc[2 * Tl][i] - m);
                    float e1 = __expf(acc[2 * Tl + 1][i] - m);
                    l += e0 + e1;
                    pa[Tl][i]     = (f16)e0;
                    pa[Tl][4 + i] = (f16)e1;
                }
            }

            #pragma unroll
            for (int Tl = 0; Tl < 4; Tl++) {
                int T = ci * 4 + Tl;
                int hd0 = q16;
                half4_t b00 = *(half4_t*)(VT + hd0 * 512 + (((8 * T + g + hd0) & 127) * 4));
                half4_t b01 = *(half4_t*)(VT + hd0 * 512 + (((8 * T + 4 + g + hd0) & 127) * 4));
                half8_t vb0;
                vb0[0] = b00[0]; vb0[1] = b00[1]; vb0[2] = b00[2]; vb0[3] = b00[3];
                vb0[4] = b01[0]; vb0[5] = b01[1]; vb0[6] = b01[2]; vb0[7] = b01[3];
                oa0 = __builtin_amdgcn_mfma_f32_16x16x32_f16(pa[Tl], vb0, oa0, 0, 0, 0);
                int hd1 = 16 + q16;
                half4_t b10 = *(half4_t*)(VT + hd1 * 512 + (((8 * T + g + hd1) & 127) * 4));
                half4_t b11 = *(half4_t*)(VT + hd1 * 512 + (((8 * T + 4 + g + hd1) & 127) * 4));
                half8_t vb1;
                vb1[0] = b10[0]; vb1[1] = b10[1]; vb1[2] = b10[2]; vb1[3] = b10[3];
                vb1[4] = b11[0]; vb1[5] = b11[1]; vb1[6] = b11[2]; vb1[7] = b11[3];
                oa1 = __builtin_amdgcn_mfma_f32_16x16x32_f16(pa[Tl], vb1, oa1, 0, 0, 0);
            }
        }

        l += __shfl_xor(l, 16);
        l += __shfl_xor(l, 32);
        float invq = 1.0f / l;
        #pragma unroll
        for (int r = 0; r < 4; r++) {
            float invr = __shfl(invq, 4 * g + r);
            size_t row = (size_t)(b * SNODES + qt * 16 + 4 * g + r);
            ao[row * CCH + hh * HDIM + q16]      = oa0[r] * invr;
            ao[row * CCH + hh * HDIM + 16 + q16] = oa1[r] * invr;
        }
    }
}

// ---------------- pooling + head ----------------
__global__ __launch_bounds__(256) void k_pool2(const float* __restrict__ h,
                                               const int* __restrict__ batch,
                                               float* __restrict__ pooled,
                                               float* __restrict__ cnt) {
    __shared__ float bins[NB_GRAPH * 132];
    __shared__ int cbin[NB_GRAPH];
    int t = threadIdx.x;
    for (int i = t; i < NB_GRAPH * 132; i += 256) bins[i] = 0.f;
    if (t < NB_GRAPH) cbin[t] = 0;
    __syncthreads();
    int n0 = blockIdx.x * 256;
    int q = t & 31, ro = t >> 5;
    float4 racc = {0.f, 0.f, 0.f, 0.f};
    int ccount = 0;
    int gcur = batch[n0 + ro];
    for (int i = 0; i < 32; i++) {
        int n = n0 + i * 8 + ro;
        int g = batch[n];
        if (g != gcur) {
            atomicAdd(&bins[gcur * 132 + 4 * q + 0], racc.x);
            atomicAdd(&bins[gcur * 132 + 4 * q + 1], racc.y);
            atomicAdd(&bins[gcur * 132 + 4 * q + 2], racc.z);
            atomicAdd(&bins[gcur * 132 + 4 * q + 3], racc.w);
            if (q == 0) atomicAdd(&cbin[gcur], ccount);
            racc = (float4){0.f, 0.f, 0.f, 0.f};
            ccount = 0;
            gcur = g;
        }
        float4 v = ((const float4*)(h + (size_t)n * CCH))[q];
        racc.x += v.x; racc.y += v.y; racc.z += v.z; racc.w += v.w;
        ccount++;
    }
    atomicAdd(&bins[gcur * 132 + 4 * q + 0], racc.x);
    atomicAdd(&bins[gcur * 132 + 4 * q + 1], racc.y);
    atomicAdd(&bins[gcur * 132 + 4 * q + 2], racc.z);
    atomicAdd(&bins[gcur * 132 + 4 * q + 3], racc.w);
    if (q == 0) atomicAdd(&cbin[gcur], ccount);
    __syncthreads();
    for (int i = t; i < NB_GRAPH * CCH; i += 256) {
        int g = i >> 7, cc = i & 127;
        float v = bins[g * 132 + cc];
        if (v != 0.f) atomicAdd(&pooled[g * CCH + cc], v);
    }
    if (t < NB_GRAPH && cbin[t]) atomicAdd(&cnt[t], (float)cbin[t]);
}

__global__ __launch_bounds__(256) void k_head(const float* __restrict__ pooled,
                                              const float* __restrict__ cnt,
                                              const float* __restrict__ Wh,
                                              const float* __restrict__ bh,
                                              const float* __restrict__ Wo,
                                              const float* __restrict__ bo,
                                              float* __restrict__ out) {
    __shared__ float p[128];
    __shared__ float red[256];
    int g = blockIdx.x, t = threadIdx.x;
    if (t < 128) p[t] = pooled[g * CCH + t] / cnt[g];
    __syncthreads();
    float a = bh[t];
    for (int k = 0; k < 128; k++) a = fmaf(p[k], Wh[k * HIDDEN + t], a);
    float z = gelu_f(a);
    red[t] = z * Wo[t];
    __syncthreads();
    for (int s = 128; s > 0; s >>= 1) {
        if (t < s) red[t] += red[t + s];
        __syncthreads();
    }
    if (t == 0) out[g] = red[0] + bo[0];
}

// ---------------- launch ----------------
extern "C" void kernel_launch(void* const* d_in, const int* in_sizes, int n_in,
                              void* d_out, int out_size, void* d_ws, size_t ws_size,
                              hipStream_t stream) {
    const float* x      = (const float*)d_in[0];
    const float* pe     = (const float*)d_in[1];
    const int*   ei     = (const int*)d_in[2];
    const int*   batch  = (const int*)d_in[3];
    const float* W_emb  = (const float*)d_in[4];
    const float* b_emb  = (const float*)d_in[5];
    const float* gcn_w  = (const float*)d_in[6];
    const float* gcn_b  = (const float*)d_in[7];
    const float* in_w   = (const float*)d_in[8];
    const float* in_b   = (const float*)d_in[9];
    const float* out_w  = (const float*)d_in[10];
    const float* out_b  = (const float*)d_in[11];
    const float* mlp_w1 = (const float*)d_in[12];
    const float* mlp_b1 = (const float*)d_in[13];
    const float* mlp_w2 = (const float*)d_in[14];
    const float* mlp_b2 = (const float*)d_in[15];
    const float* g1     = (const float*)d_in[16];
    const float* be1    = (const float*)d_in[17];
    const float* g2     = (const float*)d_in[18];
    const float* be2    = (const float*)d_in[19];
    const float* g3     = (const float*)d_in[20];
    const float* be3    = (const float*)d_in[21];
    const float* W_hid  = (const float*)d_in[22];
    const float* b_hid  = (const float*)d_in[23];
    const float* W_out  = (const float*)d_in[24];
    const float* b_out  = (const float*)d_in[25];
    float* out = (float*)d_out;

    float* ws = (float*)d_ws;
    const size_t NC = (size_t)NNODES * CCH;
    float* dinv   = ws;
    float* h      = dinv + NNODES;
    float* A      = h + NC;
    float* Bb     = A + NC;
    float* scr    = Bb + NC;                          // N*384 fp32 scratch
    float* part1  = scr + (size_t)NNODES * 384;       // 256*256
    float* part2  = part1 + 256 * 256;                // 256*256
    float* sc1    = part2 + 256 * 256;
    float* sh1    = sc1 + CCH;
    float* sc2    = sh1 + CCH;
    float* sh2    = sc2 + CCH;
    float* pooled = sh2 + CCH;                        // B*C
    float* cnt    = pooled + (size_t)NB_GRAPH * CCH;  // B
    int*   ideg   = (int*)(cnt + NB_GRAPH);           // N
    int*   rowptr = ideg + NNODES;                    // N+1
    int*   cursor = rowptr + NNODES + 1;              // N
    int*   col    = cursor + NNODES;                  // E
    f16* wb    = (f16*)(col + NEDGES);
    f16* embh  = wb;                      f16* embl = embh + 128 * 128;
    f16* cwh   = embl + 128 * 128;        f16* cwl  = cwh + 3 * 512 * 128;  // [gcn|in_w]
    f16* outh  = cwl + 3 * 512 * 128;     f16* outl = outh + 3 * 128 * 128;
    f16* m1h   = outl + 3 * 128 * 128;    f16* m1l  = m1h + 3 * 256 * 128;
    f16* m2h   = m1l + 3 * 256 * 128;     f16* m2l  = m2h + 3 * 128 * 256;
    f16* xws16 = m2l + 3 * 128 * 256;     // [N][128] f16 gather table
    f16* qkv16 = xws16 + NC;              // [N][384] f16 qkv

    const int* srcp = ei;
    const int* dstp = ei + NEDGES;

    const int NC4 = NNODES * 32;

    // ---- CSR build + dinv ----
    hipMemsetAsync(ideg, 0, NNODES * sizeof(int), stream);
    k_count<<<NEDGES / 256, 256, 0, stream>>>(dstp, ideg);
    k_scan<<<1, 1024, 0, stream>>>(ideg, rowptr, cursor, dinv);
    k_fill_edges<<<NEDGES / 256, 256, 0, stream>>>(srcp, dstp, cursor, col);

    // ---- merged weight conversion ----
    k_wconv_all<<<458752 / 256, 256, 0, stream>>>(
        W_emb, gcn_w, in_w, out_w, mlp_w1, mlp_w2,
        embh, embl, cwh, cwl, outh, outl, m1h, m1l, m2h, m2l);

    // embedding
    k_concat<<<NC4 / 256, 256, 0, stream>>>(x, pe, A);
    k_gemm_mfma<0, false, false, 0><<<dim3(1, NNODES / 128), 256, 0, stream>>>(
        A, embh, embl, b_emb, nullptr, h, NNODES, CCH, 128,
        nullptr, nullptr, nullptr, nullptr, nullptr);

    for (int l = 0; l < NLAYERS; l++) {
        // --- merged gcn|qkv GEMM ---
        k_gemm_mfma<0, true, false, 0><<<dim3(4, NNODES / 128), 256, 0, stream>>>(
            h, cwh + (size_t)l * 512 * 128, cwl + (size_t)l * 512 * 128,
            nullptr, dinv, nullptr, NNODES, 512, 128,
            qkv16, in_b + l * 384, xws16, nullptr, nullptr);
        // --- GCN branch: Bb = S1 pre-BN (without +h; stats kernel adds h) ---
        k_gcn_gather_f16<<<NNODES / 16, 256, 0, stream>>>(
            rowptr, col, xws16, dinv, gcn_b + l * CCH, Bb);
        k_bn_stats<<<128, 256, 0, stream>>>(Bb, h, part1);

        // --- attention branch: ao -> A (dead) ; outproj writes S2=acc+b+h with stats ---
        k_attn_flash<<<NB_GRAPH * NHEADS, 512, 0, stream>>>(qkv16, A);
        k_gemm_mfma<0, false, true, 1><<<dim3(1, NNODES / 128), 256, 0, stream>>>(
            A, outh + (size_t)l * 128 * 128, outl + (size_t)l * 128 * 128,
            out_b + l * CCH, nullptr, scr, NNODES, CCH, 128,
            nullptr, nullptr, nullptr, h, part2);
        k_bn_finalize2<<<1, 1024, 0, stream>>>(part1, 128, part2, 256,
            g1 + l * CCH, be1 + l * CCH, g2 + l * CCH, be2 + l * CCH,
            sc1, sh1, sc2, sh2);
        // A = bn1(Bb+h) + bn2(scr)
        k_bn_apply2<<<NC4 / 256, 256, 0, stream>>>(Bb, h, scr, sc1, sh1, sc2, sh2, A);

        // --- MLP: mlp2 writes S3=acc+b+A with stats ---
        k_gemm_mfma<1, false, false, 0><<<dim3(2, NNODES / 128), 256, 0, stream>>>(
            A, m1h + (size_t)l * 256 * 128, m1l + (size_t)l * 256 * 128,
            mlp_b1 + l * 256, nullptr, scr, NNODES, 256, 128,
            nullptr, nullptr, nullptr, nullptr, nullptr);
        k_gemm_mfma<0, false, true, 1><<<dim3(1, NNODES / 128), 256, 0, stream>>>(
            scr, m2h + (size_t)l * 128 * 256, m2l + (size_t)l * 128 * 256,
            mlp_b2 + l * CCH, nullptr, Bb, NNODES, CCH, 256,
            nullptr, nullptr, nullptr, A, part1);
        k_bn_finalize<<<1, 1024, 0, stream>>>(part1, 256, g3 + l * CCH, be3 + l * CCH, sc1, sh1);
        k_bn_apply1g<<<NC4 / 256, 256, 0, stream>>>(Bb, sc1, sh1, h);  // h = gelu(bn3(S3))
    }

    // pooling + head
    hipMemsetAsync(pooled, 0, ((size_t)NB_GRAPH * CCH + NB_GRAPH) * sizeof(float), stream);
    k_pool2<<<NNODES / 256, 256, 0, stream>>>(h, batch, pooled, cnt);
    k_head<<<NB_GRAPH, 256, 0, stream>>>(pooled, cnt, W_hid, b_hid, W_out, b_out, out);
}

// Round 18
// 777.529 us; speedup vs baseline: 1.0140x; 1.0140x over previous
//
#include <hip/hip_runtime.h>
#include <hip/hip_bf16.h>
#include <math.h>

#define NNODES 32768
#define NEDGES 524288
#define CCH 128
#define NLAYERS 3
#define NHEADS 4
#define HDIM 32
#define NB_GRAPH 64
#define SNODES 512
#define INDIM 80
#define HIDDEN 256
#define BNEPS 1e-5f
#define ATTNSCALE 0.17677669529663689f

typedef _Float16 f16;
typedef f16 half8_t __attribute__((ext_vector_type(8)));
typedef f16 half4_t __attribute__((ext_vector_type(4)));
typedef float float4_t __attribute__((ext_vector_type(4)));

__device__ __forceinline__ float gelu_f(float x) {
    return 0.5f * x * (1.0f + erff(x * 0.70710678118654752f));
}

// ---------------- CSR build ----------------
__global__ void k_count(const int* __restrict__ dst, int* __restrict__ deg) {
    int e = blockIdx.x * blockDim.x + threadIdx.x;
    if (e < NEDGES) atomicAdd(&deg[dst[e]], 1);
}

// scan + dinv fused
__global__ __launch_bounds__(1024) void k_scan(const int* __restrict__ deg,
                                               int* __restrict__ rowptr,
                                               int* __restrict__ cursor,
                                               float* __restrict__ dinv) {
    __shared__ int sa[1024], sb[1024];
    int t = threadIdx.x;
    int base = t * 32;
    int local[32];
    int s = 0;
    #pragma unroll
    for (int i = 0; i < 32; i++) {
        int d = deg[base + i];
        local[i] = s; s += d;
        dinv[base + i] = rsqrtf((float)(d + 1));
    }
    sa[t] = s;
    __syncthreads();
    int* sp = sa; int* dp = sb;
    for (int off = 1; off < 1024; off <<= 1) {
        dp[t] = (t >= off) ? sp[t] + sp[t - off] : sp[t];
        __syncthreads();
        int* tmp = sp; sp = dp; dp = tmp;
    }
    int excl = (t == 0) ? 0 : sp[t - 1];
    #pragma unroll
    for (int i = 0; i < 32; i++) {
        int v = excl + local[i];
        rowptr[base + i] = v;
        cursor[base + i] = v;
    }
    if (t == 1023) rowptr[NNODES] = sp[1023];
}

__global__ void k_fill_edges(const int* __restrict__ src, const int* __restrict__ dst,
                             int* __restrict__ cursor, int* __restrict__ col) {
    int e = blockIdx.x * blockDim.x + threadIdx.x;
    if (e >= NEDGES) return;
    int pos = atomicAdd(&cursor[dst[e]], 1);
    col[pos] = src[e];
}

// ---------------- concat (padded to K=128) ----------------
__global__ void k_concat(const float* __restrict__ x, const float* __restrict__ pe,
                         float* __restrict__ out) {
    int gid = blockIdx.x * blockDim.x + threadIdx.x;
    if (gid >= NNODES * 32) return;
    int n = gid >> 5, q = gid & 31;
    float4 v = {0.f, 0.f, 0.f, 0.f};
    if (q < 16)      v = ((const float4*)x)[(size_t)n * 16 + q];
    else if (q < 20) v = ((const float4*)pe)[(size_t)n * 4 + (q - 16)];
    ((float4*)out)[gid] = v;
}

// ---------------- merged weight conversion ----------------
__device__ __forceinline__ void wconv_one(const float* __restrict__ src,
                                          f16* __restrict__ hi, f16* __restrict__ lo,
                                          int idx, int Nn, int Ks, int Kp, int trans,
                                          int ostride) {
    int per = Nn * Kp;
    int l = idx / per, r = idx % per;
    int n = r / Kp, k = r % Kp;
    float v = 0.f;
    if (k < Ks)
        v = trans ? src[(size_t)l * Nn * Ks + (size_t)n * Ks + k]
                  : src[(size_t)l * Ks * Nn + (size_t)k * Nn + n];
    f16 h = (f16)v;
    size_t o = (size_t)l * ostride + r;
    hi[o] = h;
    lo[o] = (f16)(v - (float)h);
}

__global__ void k_wconv_all(const float* __restrict__ W_emb, const float* __restrict__ gcn_w,
                            const float* __restrict__ in_w, const float* __restrict__ out_w,
                            const float* __restrict__ m1, const float* __restrict__ m2,
                            f16* embh, f16* embl, f16* cwh, f16* cwl,
                            f16* outh, f16* outl, f16* m1h, f16* m1l,
                            f16* m2h, f16* m2l) {
    int gid = blockIdx.x * blockDim.x + threadIdx.x;
    if (gid < 16384) {
        wconv_one(W_emb, embh, embl, gid, 128, 80, 128, 0, 128 * 128);
    } else if (gid < 65536) {
        wconv_one(gcn_w, cwh, cwl, gid - 16384, 128, 128, 128, 0, 512 * 128);
    } else if (gid < 212992) {
        wconv_one(in_w, cwh + 128 * 128, cwl + 128 * 128, gid - 65536, 384, 128, 128, 1, 512 * 128);
    } else if (gid < 262144) {
        wconv_one(out_w, outh, outl, gid - 212992, 128, 128, 128, 1, 128 * 128);
    } else if (gid < 360448) {
        wconv_one(m1, m1h, m1l, gid - 262144, 256, 128, 128, 0, 256 * 128);
    } else if (gid < 458752) {
        wconv_one(m2, m2h, m2l, gid - 360448, 128, 256, 256, 0, 128 * 256);
    }
}

// ---------------- split-f16 MFMA GEMM ----------------
template<int ACT, bool SPLIT>
__global__ __launch_bounds__(256) void k_gemm_mfma(
        const float* __restrict__ A, const f16* __restrict__ Whi,
        const f16* __restrict__ Wlo, const float* __restrict__ bias,
        const float* __restrict__ rowscale, float* __restrict__ C,
        int M, int N, int K, f16* __restrict__ C2h,
        const float* __restrict__ bias2, f16* __restrict__ Cf16) {
    __shared__ f16 Ah[128 * 40];
    __shared__ f16 Al[128 * 40];
    __shared__ f16 Bh[128 * 40];
    __shared__ f16 Bl[128 * 40];
    const int t = threadIdx.x;
    const int bm = blockIdx.y * 128, bn = blockIdx.x * 128;
    const int w = t >> 6, lane = t & 63;
    const int g = lane >> 4, q = lane & 15;

    float4_t acc[2][8];
    #pragma unroll
    for (int mt = 0; mt < 2; mt++)
        #pragma unroll
        for (int nt = 0; nt < 8; nt++)
            acc[mt][nt] = (float4_t){0.f, 0.f, 0.f, 0.f};

    const int srow = t >> 1, shf = (t & 1) * 16;

    for (int kc = 0; kc < K; kc += 32) {
        {
            const float* ap = A + (size_t)(bm + srow) * K + kc + shf;
            float va[16];
            *(float4*)&va[0]  = ((const float4*)ap)[0];
            *(float4*)&va[4]  = ((const float4*)ap)[1];
            *(float4*)&va[8]  = ((const float4*)ap)[2];
            *(float4*)&va[12] = ((const float4*)ap)[3];
            half8_t h0, h1, l0, l1;
            #pragma unroll
            for (int j = 0; j < 8; j++) {
                f16 h = (f16)va[j];
                h0[j] = h; l0[j] = (f16)(va[j] - (float)h);
            }
            #pragma unroll
            for (int j = 0; j < 8; j++) {
                f16 h = (f16)va[8 + j];
                h1[j] = h; l1[j] = (f16)(va[8 + j] - (float)h);
            }
            *(half8_t*)&Ah[srow * 40 + shf]     = h0;
            *(half8_t*)&Ah[srow * 40 + shf + 8] = h1;
            *(half8_t*)&Al[srow * 40 + shf]     = l0;
            *(half8_t*)&Al[srow * 40 + shf + 8] = l1;
        }
        {
            const f16* bp = Whi + (size_t)(bn + srow) * K + kc + shf;
            *(half8_t*)&Bh[srow * 40 + shf]     = ((const half8_t*)bp)[0];
            *(half8_t*)&Bh[srow * 40 + shf + 8] = ((const half8_t*)bp)[1];
            const f16* lp = Wlo + (size_t)(bn + srow) * K + kc + shf;
            *(half8_t*)&Bl[srow * 40 + shf]     = ((const half8_t*)lp)[0];
            *(half8_t*)&Bl[srow * 40 + shf + 8] = ((const half8_t*)lp)[1];
        }
        __syncthreads();

        half8_t ah[2], al[2];
        #pragma unroll
        for (int mt = 0; mt < 2; mt++) {
            ah[mt] = *(half8_t*)&Ah[(w * 32 + mt * 16 + q) * 40 + g * 8];
            al[mt] = *(half8_t*)&Al[(w * 32 + mt * 16 + q) * 40 + g * 8];
        }
        #pragma unroll
        for (int nt = 0; nt < 8; nt++) {
            half8_t bh = *(half8_t*)&Bh[(nt * 16 + q) * 40 + g * 8];
            half8_t bl = *(half8_t*)&Bl[(nt * 16 + q) * 40 + g * 8];
            #pragma unroll
            for (int mt = 0; mt < 2; mt++) {
                acc[mt][nt] = __builtin_amdgcn_mfma_f32_16x16x32_f16(ah[mt], bh, acc[mt][nt], 0, 0, 0);
                acc[mt][nt] = __builtin_amdgcn_mfma_f32_16x16x32_f16(al[mt], bh, acc[mt][nt], 0, 0, 0);
                acc[mt][nt] = __builtin_amdgcn_mfma_f32_16x16x32_f16(ah[mt], bl, acc[mt][nt], 0, 0, 0);
            }
        }
        __syncthreads();
    }

    #pragma unroll
    for (int mt = 0; mt < 2; mt++) {
        #pragma unroll
        for (int r = 0; r < 4; r++) {
            int row = bm + w * 32 + mt * 16 + 4 * g + r;
            if constexpr (SPLIT) {
                if (blockIdx.x == 0) {
                    float rs = rowscale[row];
                    #pragma unroll
                    for (int nt = 0; nt < 8; nt++) {
                        int cn = bn + nt * 16 + q;
                        Cf16[(size_t)row * 128 + cn] = (f16)(acc[mt][nt][r] * rs);
                    }
                } else {
                    float ksc = (blockIdx.x == 2) ? ATTNSCALE : 1.0f;
                    #pragma unroll
                    for (int nt = 0; nt < 8; nt++) {
                        int cn2 = bn - 128 + nt * 16 + q;
                        C2h[(size_t)row * 384 + cn2] =
                            (f16)((acc[mt][nt][r] + bias2[cn2]) * ksc);
                    }
                }
            } else {
                float rs = rowscale ? rowscale[row] : 1.0f;
                #pragma unroll
                for (int nt = 0; nt < 8; nt++) {
                    int cn = bn + nt * 16 + q;
                    float v = acc[mt][nt][r] + (bias ? bias[cn] : 0.0f);
                    v *= rs;
                    if (ACT == 1) v = fmaxf(v, 0.0f);
                    C[(size_t)row * N + cn] = v;
                }
            }
        }
    }
}

// ---------------- GCN gather (f16 table, fp32 accum, +h residual fused) ----------------
__global__ __launch_bounds__(256) void k_gcn_gather_f16(
        const int* __restrict__ rowptr, const int* __restrict__ col,
        const f16* __restrict__ xws, const float* __restrict__ dinv,
        const float* __restrict__ bias, const float* __restrict__ resid,
        float* __restrict__ loc) {
    int t = threadIdx.x;
    int node = blockIdx.x * 16 + (t >> 4);
    int q = t & 15;
    int r0 = rowptr[node], r1 = rowptr[node + 1];
    half8_t sv = ((const half8_t*)(xws + (size_t)node * CCH))[q];
    float acc[8];
    #pragma unroll
    for (int i = 0; i < 8; i++) acc[i] = (float)sv[i];
    for (int j = r0; j < r1; j++) {
        int s = col[j];
        half8_t v = ((const half8_t*)(xws + (size_t)s * CCH))[q];
        #pragma unroll
        for (int i = 0; i < 8; i++) acc[i] += (float)v[i];
    }
    float dv = dinv[node];
    float4 b0 = ((const float4*)bias)[2 * q];
    float4 b1 = ((const float4*)bias)[2 * q + 1];
    const float* rp = resid + (size_t)node * CCH + q * 8;
    float4 r0v = ((const float4*)rp)[0];
    float4 r1v = ((const float4*)rp)[1];
    float4 o0, o1;
    o0.x = fmaf(acc[0], dv, b0.x) + r0v.x; o0.y = fmaf(acc[1], dv, b0.y) + r0v.y;
    o0.z = fmaf(acc[2], dv, b0.z) + r0v.z; o0.w = fmaf(acc[3], dv, b0.w) + r0v.w;
    o1.x = fmaf(acc[4], dv, b1.x) + r1v.x; o1.y = fmaf(acc[5], dv, b1.y) + r1v.y;
    o1.z = fmaf(acc[6], dv, b1.z) + r1v.z; o1.w = fmaf(acc[7], dv, b1.w) + r1v.w;
    float* lp = loc + (size_t)node * CCH + q * 8;
    ((float4*)lp)[0] = o0;
    ((float4*)lp)[1] = o1;
}

// ---------------- BatchNorm ----------------
// two-input stats (MLP path: S3 = A + Bb)
__global__ __launch_bounds__(256) void k_bn_stats(const float* __restrict__ a,
                                                  const float* __restrict__ b,
                                                  float* __restrict__ part) {
    __shared__ float s1[256], s2[256];
    int t = threadIdx.x, blk = blockIdx.x;
    int c = t & 127, half = t >> 7;
    float sum = 0.f, sq = 0.f;
    for (int i = 0; i < 128; i++) {
        size_t r = (size_t)blk * 256 + half + 2 * i;
        float v = a[r * CCH + c] + b[r * CCH + c];
        sum += v;
        sq = fmaf(v, v, sq);
    }
    s1[t] = sum; s2[t] = sq;
    __syncthreads();
    if (t < 128) {
        part[blk * 256 + t]       = s1[t] + s1[t + 128];
        part[blk * 256 + 128 + t] = s2[t] + s2[t + 128];
    }
}

// single-input stats (S1 already includes residual)
__global__ __launch_bounds__(256) void k_bn_stats1(const float* __restrict__ a,
                                                   float* __restrict__ part) {
    __shared__ float s1[256], s2[256];
    int t = threadIdx.x, blk = blockIdx.x;
    int c = t & 127, half = t >> 7;
    float sum = 0.f, sq = 0.f;
    for (int i = 0; i < 128; i++) {
        size_t r = (size_t)blk * 256 + half + 2 * i;
        float v = a[r * CCH + c];
        sum += v;
        sq = fmaf(v, v, sq);
    }
    s1[t] = sum; s2[t] = sq;
    __syncthreads();
    if (t < 128) {
        part[blk * 256 + t]       = s1[t] + s1[t + 128];
        part[blk * 256 + 128 + t] = s2[t] + s2[t + 128];
    }
}

// single-BN finalize (1024 thr, 8 slices)
__global__ __launch_bounds__(1024) void k_bn_finalize(const float* __restrict__ part,
                                                      const float* __restrict__ g,
                                                      const float* __restrict__ be,
                                                      float* __restrict__ sc,
                                                      float* __restrict__ sh) {
    __shared__ float rs_[1024], rq_[1024];
    int t = threadIdx.x;
    int c = t & 127, sl = t >> 7;
    float s = 0.f, sq = 0.f;
    for (int bk = sl; bk < 128; bk += 8) {
        s  += part[bk * 256 + c];
        sq += part[bk * 256 + 128 + c];
    }
    rs_[sl * 128 + c] = s;
    rq_[sl * 128 + c] = sq;
    __syncthreads();
    if (t < 128) {
        float ss = 0.f, qq = 0.f;
        #pragma unroll
        for (int k = 0; k < 8; k++) { ss += rs_[k * 128 + t]; qq += rq_[k * 128 + t]; }
        float mu = ss / (float)NNODES;
        float var = qq / (float)NNODES - mu * mu;
        float rsv = rsqrtf(var + BNEPS);
        float gg = g[t] * rsv;
        sc[t] = gg;
        sh[t] = be[t] - mu * gg;
    }
}

// dual-BN finalize
__global__ __launch_bounds__(1024) void k_bn_finalize2(
        const float* __restrict__ part1, const float* __restrict__ part2,
        const float* __restrict__ g1, const float* __restrict__ be1,
        const float* __restrict__ g2, const float* __restrict__ be2,
        float* __restrict__ sc1, float* __restrict__ sh1,
        float* __restrict__ sc2, float* __restrict__ sh2) {
    __shared__ float rs_[1024], rq_[1024];
    int t = threadIdx.x;
    int c = t & 127, sl = t >> 7;
    const float* p = (sl < 4) ? part1 : part2;
    int s0 = sl & 3;
    float s = 0.f, sq = 0.f;
    for (int bk = s0; bk < 128; bk += 4) {
        s  += p[bk * 256 + c];
        sq += p[bk * 256 + 128 + c];
    }
    rs_[sl * 128 + c] = s;
    rq_[sl * 128 + c] = sq;
    __syncthreads();
    if (t < 256) {
        int which = t >> 7, cc = t & 127;
        int o = which * 512;
        float ss = 0.f, qq = 0.f;
        #pragma unroll
        for (int k = 0; k < 4; k++) { ss += rs_[o + k * 128 + cc]; qq += rq_[o + k * 128 + cc]; }
        float mu = ss / (float)NNODES;
        float var = qq / (float)NNODES - mu * mu;
        float rsv = rsqrtf(var + BNEPS);
        if (which == 0) { float gg = g1[cc] * rsv; sc1[cc] = gg; sh1[cc] = be1[cc] - mu * gg; }
        else            { float gg = g2[cc] * rsv; sc2[cc] = gg; sh2[cc] = be2[cc] - mu * gg; }
    }
}

// out = act((a+b)*sc + sh)
template<int ACT>
__global__ void k_bn_apply(const float* __restrict__ a, const float* __restrict__ b,
                           const float* __restrict__ sc, const float* __restrict__ sh,
                           float* __restrict__ out) {
    int gid = blockIdx.x * blockDim.x + threadIdx.x;
    if (gid >= NNODES * 32) return;
    int c = (gid & 31) * 4;
    float4 av = ((const float4*)a)[gid];
    float4 bv = ((const float4*)b)[gid];
    float r[4];
    float xs[4] = {av.x + bv.x, av.y + bv.y, av.z + bv.z, av.w + bv.w};
    #pragma unroll
    for (int j = 0; j < 4; j++) {
        float v = fmaf(xs[j], sc[c + j], sh[c + j]);
        if (ACT == 2) v = gelu_f(v);
        r[j] = v;
    }
    float4 o = {r[0], r[1], r[2], r[3]};
    ((float4*)out)[gid] = o;
}

// A = bn1(Bb) + bn2(scr+h)   (Bb already holds S1 = gather + h)
__global__ void k_bn_apply2(const float* __restrict__ Bb, const float* __restrict__ h,
                            const float* __restrict__ scr,
                            const float* __restrict__ sc1, const float* __restrict__ sh1,
                            const float* __restrict__ sc2, const float* __restrict__ sh2,
                            float* __restrict__ A) {
    int gid = blockIdx.x * blockDim.x + threadIdx.x;
    if (gid >= NNODES * 32) return;
    int c = (gid & 31) * 4;
    float4 bv = ((const float4*)Bb)[gid];
    float4 hv = ((const float4*)h)[gid];
    float4 sv = ((const float4*)scr)[gid];
    float b4[4] = {bv.x, bv.y, bv.z, bv.w};
    float h4[4] = {hv.x, hv.y, hv.z, hv.w};
    float s4[4] = {sv.x, sv.y, sv.z, sv.w};
    float r[4];
    #pragma unroll
    for (int j = 0; j < 4; j++) {
        float x2 = s4[j] + h4[j];
        r[j] = fmaf(b4[j], sc1[c + j], sh1[c + j]) + fmaf(x2, sc2[c + j], sh2[c + j]);
    }
    float4 o = {r[0], r[1], r[2], r[3]};
    ((float4*)A)[gid] = o;
}

// ---------------- flash MFMA attention (f16 qkv input; 512 threads, 8 waves) ----------
__global__ __launch_bounds__(512) void k_attn_flash(const f16* __restrict__ qkv,
                                                    float* __restrict__ ao) {
    __shared__ f16 Ks[512 * 40];
    __shared__ f16 VT[32 * 512];
    const int bh = blockIdx.x;
    const int b = bh >> 2, hh = bh & 3;
    const int t = threadIdx.x;
    const int lane = t & 63, wave = t >> 6;
    const int g = lane >> 4, q16 = lane & 15;

    const f16* base = qkv + (size_t)b * SNODES * 384;

    #pragma unroll
    for (int it = 0; it < 4; it++) {
        int u = it * 512 + t;
        int row = u >> 2, c = u & 3;
        half8_t hv = *(const half8_t*)(base + (size_t)row * 384 + CCH + hh * HDIM + c * 8);
        *(half8_t*)(Ks + row * 40 + c * 8) = hv;
    }

    #pragma unroll
    for (int it = 0; it < 8; it++) {
        int j4 = (t >> 3) & 3;
        int n  = it * 64 + ((t >> 5) & 15) * 4 + j4;
        int c  = t & 7;
        half4_t hv = *(const half4_t*)(base + (size_t)n * 384 + 2 * CCH + hh * HDIM + c * 4);
        float4 v = {(float)hv[0], (float)hv[1], (float)hv[2], (float)hv[3]};
        float4 u1;
        u1.x = __shfl_xor(v.x, 8); u1.y = __shfl_xor(v.y, 8);
        u1.z = __shfl_xor(v.z, 8); u1.w = __shfl_xor(v.w, 8);
        float4 w;
        if ((t & 8) == 0) { w.x = v.x;  w.y = u1.x; w.z = v.z;  w.w = u1.z; }
        else              { w.x = u1.y; w.y = v.y;  w.z = u1.w; w.w = v.w;  }
        float4 u2;
        u2.x = __shfl_xor(w.x, 16); u2.y = __shfl_xor(w.y, 16);
        u2.z = __shfl_xor(w.z, 16); u2.w = __shfl_xor(w.w, 16);
        float4 o;
        if ((t & 16) == 0) { o.x = w.x;  o.y = w.y;  o.z = u2.x; o.w = u2.y; }
        else               { o.x = u2.z; o.y = u2.w; o.z = w.z;  o.w = w.w;  }
        int hd = c * 4 + j4;
        int n0 = it * 64 + ((t >> 5) & 15) * 4;
        half4_t pk;
        pk[0] = (f16)o.x; pk[1] = (f16)o.y; pk[2] = (f16)o.z; pk[3] = (f16)o.w;
        int pos = ((n0 >> 2) + hd) & 127;
        *(half4_t*)(VT + hd * 512 + pos * 4) = pk;
    }
    __syncthreads();

    for (int j = 0; j < 4; j++) {
        int qt = wave * 4 + j;

        half8_t qf = *(const half8_t*)(base + (size_t)(qt * 16 + q16) * 384 + hh * HDIM + g * 8);

        float m = -1e30f, l = 0.f;
        float4_t oa0 = {0.f, 0.f, 0.f, 0.f}, oa1 = {0.f, 0.f, 0.f, 0.f};

        for (int ci = 0; ci < 4; ci++) {
            float4_t acc[8];
            #pragma unroll
            for (int ktl = 0; ktl < 8; ktl++) {
                half8_t kf = *(half8_t*)(Ks + ((ci * 8 + ktl) * 16 + q16) * 40 + g * 8);
                float4_t z = {0.f, 0.f, 0.f, 0.f};
                acc[ktl] = __builtin_amdgcn_mfma_f32_16x16x32_f16(kf, qf, z, 0, 0, 0);
            }

            float cm = -1e30f;
            #pragma unroll
            for (int ktl = 0; ktl < 8; ktl++)
                cm = fmaxf(cm, fmaxf(fmaxf(acc[ktl][0], acc[ktl][1]),
                                     fmaxf(acc[ktl][2], acc[ktl][3])));
            cm = fmaxf(cm, __shfl_xor(cm, 16));
            cm = fmaxf(cm, __shfl_xor(cm, 32));

            float mn = fmaxf(m, cm);
            float scq = __expf(m - mn);
            m = mn;
            l *= scq;
            #pragma unroll
            for (int r = 0; r < 4; r++) {
                float scr_ = __shfl(scq, 4 * g + r);
                oa0[r] *= scr_;
                oa1[r] *= scr_;
            }

            half8_t pa[4];
            #pragma unroll
            for (int Tl = 0; Tl < 4; Tl++) {
                #pragma unroll
                for (int i = 0; i < 4; i++) {
                    float e0 = __expf(acc[2 * Tl][i] - m);
                    float e1 = __expf(acc[2 * Tl + 1][i] - m);
                    l += e0 + e1;
                    pa[Tl][i]     = (f16)e0;
                    pa[Tl][4 + i] = (f16)e1;
                }
            }

            #pragma unroll
            for (int Tl = 0; Tl < 4; Tl++) {
                int T = ci * 4 + Tl;
                int hd0 = q16;
                half4_t b00 = *(half4_t*)(VT + hd0 * 512 + (((8 * T + g + hd0) & 127) * 4));
                half4_t b01 = *(half4_t*)(VT + hd0 * 512 + (((8 * T + 4 + g + hd0) & 127) * 4));
                half8_t vb0;
                vb0[0] = b00[0]; vb0[1] = b00[1]; vb0[2] = b00[2]; vb0[3] = b00[3];
                vb0[4] = b01[0]; vb0[5] = b01[1]; vb0[6] = b01[2]; vb0[7] = b01[3];
                oa0 = __builtin_amdgcn_mfma_f32_16x16x32_f16(pa[Tl], vb0, oa0, 0, 0, 0);
                int hd1 = 16 + q16;
                half4_t b10 = *(half4_t*)(VT + hd1 * 512 + (((8 * T + g + hd1) & 127) * 4));
                half4_t b11 = *(half4_t*)(VT + hd1 * 512 + (((8 * T + 4 + g + hd1) & 127) * 4));
                half8_t vb1;
                vb1[0] = b10[0]; vb1[1] = b10[1]; vb1[2] = b10[2]; vb1[3] = b10[3];
                vb1[4] = b11[0]; vb1[5] = b11[1]; vb1[6] = b11[2]; vb1[7] = b11[3];
                oa1 = __builtin_amdgcn_mfma_f32_16x16x32_f16(pa[Tl], vb1, oa1, 0, 0, 0);
            }
        }

        l += __shfl_xor(l, 16);
        l += __shfl_xor(l, 32);
        float invq = 1.0f / l;
        #pragma unroll
        for (int r = 0; r < 4; r++) {
            float invr = __shfl(invq, 4 * g + r);
            size_t row = (size_t)(b * SNODES + qt * 16 + 4 * g + r);
            ao[row * CCH + hh * HDIM + q16]      = oa0[r] * invr;
            ao[row * CCH + hh * HDIM + 16 + q16] = oa1[r] * invr;
        }
    }
}

// ---------------- pooling + head ----------------
__global__ __launch_bounds__(256) void k_pool2(const float* __restrict__ h,
                                               const int* __restrict__ batch,
                                               float* __restrict__ pooled,
                                               float* __restrict__ cnt) {
    __shared__ float bins[NB_GRAPH * 132];
    __shared__ int cbin[NB_GRAPH];
    int t = threadIdx.x;
    for (int i = t; i < NB_GRAPH * 132; i += 256) bins[i] = 0.f;
    if (t < NB_GRAPH) cbin[t] = 0;
    __syncthreads();
    int n0 = blockIdx.x * 256;
    int q = t & 31, ro = t >> 5;
    float4 racc = {0.f, 0.f, 0.f, 0.f};
    int ccount = 0;
    int gcur = batch[n0 + ro];
    for (int i = 0; i < 32; i++) {
        int n = n0 + i * 8 + ro;
        int g = batch[n];
        if (g != gcur) {
            atomicAdd(&bins[gcur * 132 + 4 * q + 0], racc.x);
            atomicAdd(&bins[gcur * 132 + 4 * q + 1], racc.y);
            atomicAdd(&bins[gcur * 132 + 4 * q + 2], racc.z);
            atomicAdd(&bins[gcur * 132 + 4 * q + 3], racc.w);
            if (q == 0) atomicAdd(&cbin[gcur], ccount);
            racc = (float4){0.f, 0.f, 0.f, 0.f};
            ccount = 0;
            gcur = g;
        }
        float4 v = ((const float4*)(h + (size_t)n * CCH))[q];
        racc.x += v.x; racc.y += v.y; racc.z += v.z; racc.w += v.w;
        ccount++;
    }
    atomicAdd(&bins[gcur * 132 + 4 * q + 0], racc.x);
    atomicAdd(&bins[gcur * 132 + 4 * q + 1], racc.y);
    atomicAdd(&bins[gcur * 132 + 4 * q + 2], racc.z);
    atomicAdd(&bins[gcur * 132 + 4 * q + 3], racc.w);
    if (q == 0) atomicAdd(&cbin[gcur], ccount);
    __syncthreads();
    for (int i = t; i < NB_GRAPH * CCH; i += 256) {
        int g = i >> 7, cc = i & 127;
        float v = bins[g * 132 + cc];
        if (v != 0.f) atomicAdd(&pooled[g * CCH + cc], v);
    }
    if (t < NB_GRAPH && cbin[t]) atomicAdd(&cnt[t], (float)cbin[t]);
}

__global__ __launch_bounds__(256) void k_head(const float* __restrict__ pooled,
                                              const float* __restrict__ cnt,
                                              const float* __restrict__ Wh,
                                              const float* __restrict__ bh,
                                              const float* __restrict__ Wo,
                                              const float* __restrict__ bo,
                                              float* __restrict__ out) {
    __shared__ float p[128];
    __shared__ float red[256];
    int g = blockIdx.x, t = threadIdx.x;
    if (t < 128) p[t] = pooled[g * CCH + t] / cnt[g];
    __syncthreads();
    float a = bh[t];
    for (int k = 0; k < 128; k++) a = fmaf(p[k], Wh[k * HIDDEN + t], a);
    float z = gelu_f(a);
    red[t] = z * Wo[t];
    __syncthreads();
    for (int s = 128; s > 0; s >>= 1) {
        if (t < s) red[t] += red[t + s];
        __syncthreads();
    }
    if (t == 0) out[g] = red[0] + bo[0];
}

// ---------------- launch ----------------
extern "C" void kernel_launch(void* const* d_in, const int* in_sizes, int n_in,
                              void* d_out, int out_size, void* d_ws, size_t ws_size,
                              hipStream_t stream) {
    const float* x      = (const float*)d_in[0];
    const float* pe     = (const float*)d_in[1];
    const int*   ei     = (const int*)d_in[2];
    const int*   batch  = (const int*)d_in[3];
    const float* W_emb  = (const float*)d_in[4];
    const float* b_emb  = (const float*)d_in[5];
    const float* gcn_w  = (const float*)d_in[6];
    const float* gcn_b  = (const float*)d_in[7];
    const float* in_w   = (const float*)d_in[8];
    const float* in_b   = (const float*)d_in[9];
    const float* out_w  = (const float*)d_in[10];
    const float* out_b  = (const float*)d_in[11];
    const float* mlp_w1 = (const float*)d_in[12];
    const float* mlp_b1 = (const float*)d_in[13];
    const float* mlp_w2 = (const float*)d_in[14];
    const float* mlp_b2 = (const float*)d_in[15];
    const float* g1     = (const float*)d_in[16];
    const float* be1    = (const float*)d_in[17];
    const float* g2     = (const float*)d_in[18];
    const float* be2    = (const float*)d_in[19];
    const float* g3     = (const float*)d_in[20];
    const float* be3    = (const float*)d_in[21];
    const float* W_hid  = (const float*)d_in[22];
    const float* b_hid  = (const float*)d_in[23];
    const float* W_out  = (const float*)d_in[24];
    const float* b_out  = (const float*)d_in[25];
    float* out = (float*)d_out;

    float* ws = (float*)d_ws;
    const size_t NC = (size_t)NNODES * CCH;
    float* dinv   = ws;
    float* h      = dinv + NNODES;
    float* A      = h + NC;
    float* Bb     = A + NC;
    float* scr    = Bb + NC;                          // N*384 fp32 scratch
    float* part1  = scr + (size_t)NNODES * 384;       // 128*256
    float* part2  = part1 + 128 * 256;                // 128*256
    float* sc1    = part2 + 128 * 256;
    float* sh1    = sc1 + CCH;
    float* sc2    = sh1 + CCH;
    float* sh2    = sc2 + CCH;
    float* pooled = sh2 + CCH;                        // B*C
    float* cnt    = pooled + (size_t)NB_GRAPH * CCH;  // B
    int*   ideg   = (int*)(cnt + NB_GRAPH);           // N
    int*   rowptr = ideg + NNODES;                    // N+1
    int*   cursor = rowptr + NNODES + 1;              // N
    int*   col    = cursor + NNODES;                  // E
    f16* wb    = (f16*)(col + NEDGES);
    f16* embh  = wb;                      f16* embl = embh + 128 * 128;
    f16* cwh   = embl + 128 * 128;        f16* cwl  = cwh + 3 * 512 * 128;  // [gcn|in_w]
    f16* outh  = cwl + 3 * 512 * 128;     f16* outl = outh + 3 * 128 * 128;
    f16* m1h   = outl + 3 * 128 * 128;    f16* m1l  = m1h + 3 * 256 * 128;
    f16* m2h   = m1l + 3 * 256 * 128;     f16* m2l  = m2h + 3 * 128 * 256;
    f16* xws16 = m2l + 3 * 128 * 256;     // [N][128] f16 gather table
    f16* qkv16 = xws16 + NC;              // [N][384] f16 qkv

    const int* srcp = ei;
    const int* dstp = ei + NEDGES;

    const int NC4 = NNODES * 32;

    // ---- CSR build + dinv ----
    hipMemsetAsync(ideg, 0, NNODES * sizeof(int), stream);
    k_count<<<NEDGES / 256, 256, 0, stream>>>(dstp, ideg);
    k_scan<<<1, 1024, 0, stream>>>(ideg, rowptr, cursor, dinv);
    k_fill_edges<<<NEDGES / 256, 256, 0, stream>>>(srcp, dstp, cursor, col);

    // ---- merged weight conversion ----
    k_wconv_all<<<458752 / 256, 256, 0, stream>>>(
        W_emb, gcn_w, in_w, out_w, mlp_w1, mlp_w2,
        embh, embl, cwh, cwl, outh, outl, m1h, m1l, m2h, m2l);

    // embedding
    k_concat<<<NC4 / 256, 256, 0, stream>>>(x, pe, A);
    k_gemm_mfma<0, false><<<dim3(1, NNODES / 128), 256, 0, stream>>>(
        A, embh, embl, b_emb, nullptr, h, NNODES, CCH, 128, nullptr, nullptr, nullptr);

    for (int l = 0; l < NLAYERS; l++) {
        // --- merged gcn|qkv GEMM ---
        k_gemm_mfma<0, true><<<dim3(4, NNODES / 128), 256, 0, stream>>>(
            h, cwh + (size_t)l * 512 * 128, cwl + (size_t)l * 512 * 128,
            nullptr, dinv, nullptr, NNODES, 512, 128, qkv16, in_b + l * 384, xws16);
        // --- GCN branch: Bb = S1 = gather + h (residual fused) ---
        k_gcn_gather_f16<<<NNODES / 16, 256, 0, stream>>>(
            rowptr, col, xws16, dinv, gcn_b + l * CCH, h, Bb);
        k_bn_stats1<<<128, 256, 0, stream>>>(Bb, part1);

        // --- attention branch: ao -> A (A is dead here) ---
        k_attn_flash<<<NB_GRAPH * NHEADS, 512, 0, stream>>>(qkv16, A);
        k_gemm_mfma<0, false><<<dim3(1, NNODES / 128), 256, 0, stream>>>(
            A, outh + (size_t)l * 128 * 128, outl + (size_t)l * 128 * 128,
            out_b + l * CCH, nullptr, scr, NNODES, CCH, 128, nullptr, nullptr, nullptr);
        k_bn_stats<<<128, 256, 0, stream>>>(scr, h, part2);
        k_bn_finalize2<<<1, 1024, 0, stream>>>(part1, part2,
            g1 + l * CCH, be1 + l * CCH, g2 + l * CCH, be2 + l * CCH,
            sc1, sh1, sc2, sh2);
        // A = bn1(Bb) + bn2(scr+h)
        k_bn_apply2<<<NC4 / 256, 256, 0, stream>>>(Bb, h, scr, sc1, sh1, sc2, sh2, A);

        // --- MLP ---
        k_gemm_mfma<1, false><<<dim3(2, NNODES / 128), 256, 0, stream>>>(
            A, m1h + (size_t)l * 256 * 128, m1l + (size_t)l * 256 * 128,
            mlp_b1 + l * 256, nullptr, scr, NNODES, 256, 128, nullptr, nullptr, nullptr);
        k_gemm_mfma<0, false><<<dim3(1, NNODES / 128), 256, 0, stream>>>(
            scr, m2h + (size_t)l * 128 * 256, m2l + (size_t)l * 128 * 256,
            mlp_b2 + l * CCH, nullptr, Bb, NNODES, CCH, 256, nullptr, nullptr, nullptr);
        k_bn_stats<<<128, 256, 0, stream>>>(A, Bb, part1);
        k_bn_finalize<<<1, 1024, 0, stream>>>(part1, g3 + l * CCH, be3 + l * CCH, sc1, sh1);
        k_bn_apply<2><<<NC4 / 256, 256, 0, stream>>>(A, Bb, sc1, sh1, h);  // h = gelu(bn)
    }

    // pooling + head
    hipMemsetAsync(pooled, 0, ((size_t)NB_GRAPH * CCH + NB_GRAPH) * sizeof(float), stream);
    k_pool2<<<NNODES / 256, 256, 0, stream>>>(h, batch, pooled, cnt);
    k_head<<<NB_GRAPH, 256, 0, stream>>>(pooled, cnt, W_hid, b_hid, W_out, b_out, out);
}